// Round 3
// baseline (304.205 us; speedup 1.0000x reference)
//
#include <hip/hip_runtime.h>
#include <math.h>

#define HALF 64
#define LN_EPS 1e-5f
#define SA_CAP 640   // staged float4 slots per block (10 KB); Poisson(256)+24sigma

// gelu_tanh(x) = x * sigmoid(1.5957691*x + 0.0713549*x^3)
#define GC0 -2.3022082f
#define GC1 -0.1029438f

__device__ __forceinline__ float gelu_fast(float x) {
    const float x2 = x * x;
    const float z  = x * fmaf(GC1, x2, GC0);
    const float e  = __builtin_amdgcn_exp2f(z);
    const float sg = __builtin_amdgcn_rcpf(1.0f + e);
    return x * sg;
}

// ---------------------------------------------------------------------------
// histogram of dst (count only — rank is now derived in fill via the scanned
// cursor, saving a 6.4 MB write here + 6.4 MB read there)
// ---------------------------------------------------------------------------
__global__ void __launch_bounds__(256) hist_kernel(
    const int* __restrict__ dst, int* __restrict__ cursor, int E)
{
    const int e4 = (blockIdx.x * 256 + threadIdx.x) * 4;
    if (e4 + 3 < E) {
        const int4 d = *(const int4*)(dst + e4);
        atomicAdd(&cursor[d.x], 1);
        atomicAdd(&cursor[d.y], 1);
        atomicAdd(&cursor[d.z], 1);
        atomicAdd(&cursor[d.w], 1);
    } else {
        for (int e = e4; e < E; ++e) atomicAdd(&cursor[dst[e]], 1);
    }
}

// ---------------------------------------------------------------------------
// PARALLEL exclusive scan (decoupled lookback). Writes the exclusive prefix
// to BOTH offsets[] (read-only CSR for nodeout) and cursor[] (working copy:
// fill's atomicAdd on it returns the final slot = offsets[d]+rank fused).
// Block 0 wave 0 also computes the analytic-LN constants fp[0..13].
// ---------------------------------------------------------------------------
__global__ void __launch_bounds__(1024) scan_kernel(
    const int* __restrict__ cursorIn, int* __restrict__ cursorOut,
    int* __restrict__ offsets, int* __restrict__ stat,
    const float* __restrict__ W1, const float* __restrict__ b1,
    float* __restrict__ fp, int N)
{
    const int t = threadIdx.x;
    const int b = blockIdx.x;
    if (b == 0 && t < 64) {
        const float w0 = W1[t], w1 = W1[HALF + t], w2 = W1[2 * HALF + t], bb = b1[t];
        float v[14] = { w0, w1, w2, bb,
                        w0 * w0, w0 * w1, w0 * w2, w1 * w1, w1 * w2, w2 * w2,
                        w0 * bb, w1 * bb, w2 * bb, bb * bb };
#pragma unroll
        for (int j = 0; j < 14; ++j) {
            float s = v[j];
#pragma unroll
            for (int off = 32; off; off >>= 1) s += __shfl_down(s, off, 64);
            if (t == 0) fp[j] = s * (1.0f / 64.0f);
        }
    }

    __shared__ int wtot[16];
    __shared__ int wexc[16];
    __shared__ int stot;
    __shared__ int sPref;
    const int w = t >> 6, lane = t & 63;

    const int i0 = b * 4096 + t * 4;
    int c[4];
    if (i0 + 3 < N) {
        *(int4*)c = *(const int4*)(cursorIn + i0);
    } else {
#pragma unroll
        for (int j = 0; j < 4; ++j) c[j] = (i0 + j < N) ? cursorIn[i0 + j] : 0;
    }
    const int s = c[0] + c[1] + c[2] + c[3];
    int incl = s;
#pragma unroll
    for (int off = 1; off < 64; off <<= 1) {
        const int v = __shfl_up(incl, off, 64);
        if (lane >= off) incl += v;
    }
    if (lane == 63) wtot[w] = incl;
    __syncthreads();
    if (t < 16) {
        const int v = wtot[t];
        int inc2 = v;
#pragma unroll
        for (int off = 1; off < 16; off <<= 1) {
            const int u = __shfl_up(inc2, off, 64);
            if (t >= off) inc2 += u;
        }
        wexc[t] = inc2 - v;
        if (t == 15) stot = inc2;
    }
    __syncthreads();

    if (t == 0) {
        const int S = stot;
        if (b == 0) {
            sPref = 0;
            __hip_atomic_store(&stat[0], (S << 2) | 2, __ATOMIC_RELEASE,
                               __HIP_MEMORY_SCOPE_AGENT);
        } else {
            __hip_atomic_store(&stat[b], (S << 2) | 1, __ATOMIC_RELEASE,
                               __HIP_MEMORY_SCOPE_AGENT);
            int running = 0;
            int j = b - 1;
            while (true) {
                const int v = __hip_atomic_load(&stat[j], __ATOMIC_ACQUIRE,
                                                __HIP_MEMORY_SCOPE_AGENT);
                const int st = v & 3;
                if (st == 0) continue;          // predecessor not published yet
                running += v >> 2;
                if (st == 2) break;             // hit a full prefix
                --j;
            }
            sPref = running;
            __hip_atomic_store(&stat[b], ((running + S) << 2) | 2,
                               __ATOMIC_RELEASE, __HIP_MEMORY_SCOPE_AGENT);
        }
    }
    __syncthreads();

    int run = sPref + wexc[w] + (incl - s);
#pragma unroll
    for (int j = 0; j < 4; ++j) {
        const int i = i0 + j;
        if (i < N) { offsets[i] = run; cursorOut[i] = run; }
        run += c[j];
    }
    if (t == 0 && b == (int)gridDim.x - 1) offsets[N] = sPref + stot;
}

// ---------------------------------------------------------------------------
// fill: slot = atomicAdd(&cursor[dst], 1) — cursor holds the scanned prefix,
// so the atomic's return value IS the final CSR slot (offsets[d]+rank fused).
// ---------------------------------------------------------------------------
__global__ void __launch_bounds__(256) fill_kernel(
    const int* __restrict__ ei, const float* __restrict__ pos,
    const float* __restrict__ fp, int* __restrict__ cursor,
    float4* __restrict__ A, int E)
{
    const int e4 = (blockIdx.x * 256 + threadIdx.x) * 4;
    if (e4 >= E) return;

    int se[4], de[4];
    if (e4 + 3 < E) {
        *(int4*)se = *(const int4*)(ei + e4);
        *(int4*)de = *(const int4*)(ei + E + e4);
    } else {
        for (int j = 0; j < 4; ++j) {
            const int e = e4 + j;
            se[j] = (e < E) ? ei[e] : 0;
            de[j] = (e < E) ? ei[E + e] : 0;
        }
    }
    const float ux = fp[0], uy = fp[1], uz = fp[2], cc = fp[3];
    const float Gxx = fp[4], Gxy = fp[5], Gxz = fp[6];
    const float Gyy = fp[7], Gyz = fp[8], Gzz = fp[9];
    const float px = fp[10], py = fp[11], pz = fp[12], qq = fp[13];

#pragma unroll
    for (int j = 0; j < 4; ++j) {
        const int e = e4 + j;
        if (e >= E) break;
        const int s = se[j], d = de[j];
        const float rx0 = pos[3 * d + 0] - pos[3 * s + 0];
        const float ry0 = pos[3 * d + 1] - pos[3 * s + 1];
        const float rz0 = pos[3 * d + 2] - pos[3 * s + 2];
        const float dist = sqrtf(rx0 * rx0 + ry0 * ry0 + rz0 * rz0);
        const float inv  = 1.0f / (dist + 1e-6f);
        const float rx = rx0 * inv, ry = ry0 * inv, rz = rz0 * inv;

        const float mu  = fmaf(ux, rx, fmaf(uy, ry, fmaf(uz, rz, cc)));
        const float ev2 = Gxx * rx * rx + Gyy * ry * ry + Gzz * rz * rz
                        + 2.0f * (Gxy * rx * ry + Gxz * rx * rz + Gyz * ry * rz
                                  + px * rx + py * ry + pz * rz) + qq;
        const float rstd = rsqrtf(ev2 - mu * mu + LN_EPS);

        const int slot = atomicAdd(&cursor[d], 1);
        A[slot] = make_float4(rx * rstd, ry * rstd, rz * rstd, rstd);
    }
}

// ---------------------------------------------------------------------------
// FUSED node+out kernel v4: 16 nodes/block, 4 waves x 4 nodes.
// Phase 1: block-wide coalesced LDS stage (one barrier), then each wave
// processes its 4 nodes' CONTIGUOUS edge range as ONE merged chunk-of-8
// stream — wave-uniform boundary-flush (SALU) removes the ~20% per-node
// ceil-to-8 tail waste of v3.
// Phase 2 (wave-private, NO second barrier): lane c holds W2[:,c] in 64
// VGPRs (coalesced global loads, L2-hot); sh reads are uniform broadcasts.
// Removes sW2 (16 KB LDS + 262 KB/block of LDS reads = ~2 GB/dispatch, the
// v3 phase-2 LDS-bandwidth bottleneck). Stores stay coalesced (lane=col).
// LDS ~14.5 KB; launch_bounds(256,4) targets 128 VGPR / 16 waves/CU.
// ---------------------------------------------------------------------------
__global__ void __launch_bounds__(256, 4) nodeout_kernel(
    const float4* __restrict__ A,        // [E+16] CSR-ordered (padded)
    const int* __restrict__ offsets,     // [N+1]
    const float* __restrict__ W1, const float* __restrict__ b1,
    const float* __restrict__ ln_g, const float* __restrict__ ln_b,
    const float* __restrict__ W2, const float* __restrict__ b2,
    const float* __restrict__ fp,
    float* __restrict__ out, int N)
{
    __shared__ float4 sA[SA_CAP + 8];    // 10.4 KB (+8 pad for chunk overread)
    __shared__ float  sh[16 * 64];       // 4 KB; writes 2-way-free, reads bcast

    const int tid = threadIdx.x;
    const int lane = tid & 63, w = tid >> 6;

    const float gl = ln_g[lane];
    const float C0 = gl * (W1[lane]            - fp[0]);
    const float C1 = gl * (W1[HALF + lane]     - fp[1]);
    const float C2 = gl * (W1[2 * HALF + lane] - fp[2]);
    const float C3 = gl * (b1[lane]            - fp[3]);
    const float Bl = ln_b[lane];
    const float b2l = b2[lane];

    const int base = blockIdx.x * 16;
    const int nend = (base + 16 < N) ? base + 16 : N;
    const int begB = offsets[base];
    const int cntB = offsets[nend] - begB;

    // wave's 4-node CSR bounds (clamped indices keep ranges contiguous)
    const int n0 = base + w * 4;
    const int o0 = offsets[(n0     < N) ? n0     : N];
    const int o1 = offsets[(n0 + 1 < N) ? n0 + 1 : N];
    const int o2 = offsets[(n0 + 2 < N) ? n0 + 2 : N];
    const int o3 = offsets[(n0 + 3 < N) ? n0 + 3 : N];
    const int o4 = offsets[(n0 + 4 < N) ? n0 + 4 : N];
    const int c0 = o1 - o0, c1 = o2 - o1, c2 = o3 - o2, c3 = o4 - o3;
    const int e1 = c0, e2 = c0 + c1, e3 = c0 + c1 + c2;
    const int wcnt = c0 + c1 + c2 + c3;
    const float i0 = (c0 > 0) ? 1.0f / (float)c0 : 0.0f;
    const float i1 = (c1 > 0) ? 1.0f / (float)c1 : 0.0f;
    const float i2 = (c2 > 0) ? 1.0f / (float)c2 : 0.0f;
    const float i3 = (c3 > 0) ? 1.0f / (float)c3 : 0.0f;

    const bool fast = (cntB <= SA_CAP);
    if (fast) {
        for (int i = tid; i < cntB; i += 256) sA[i] = A[begB + i];
    }
    __syncthreads();

    // flush: write node q's mean row (select chains — no runtime-indexed
    // arrays, which would spill to scratch)
    int q = 0, nextEnd = e1;
    float accA = 0.0f, accB = 0.0f;
#define FLUSH_ROW()                                                         \
    {                                                                       \
        const float inv = (q == 0) ? i0 : (q == 1) ? i1 : (q == 2) ? i2 : i3; \
        sh[(w * 4 + q) * 64 + lane] = (accA + accB) * inv;                  \
        accA = 0.0f; accB = 0.0f; ++q;                                      \
        nextEnd = (q == 1) ? e2 : (q == 2) ? e3 : (q == 3) ? wcnt : 0x7fffffff; \
    }

    if (fast) {
        const int off = o0 - begB;
        for (int i = 0; i < wcnt; i += 8) {
            float4 aa[8];
#pragma unroll
            for (int j = 0; j < 8; ++j) aa[j] = sA[off + i + j];
#pragma unroll
            for (int j = 0; j < 8; ++j) {
                const int idx = i + j;
                while (q < 4 && idx == nextEnd) FLUSH_ROW();
                const float x = fmaf(C0, aa[j].x, fmaf(C1, aa[j].y,
                                  fmaf(C2, aa[j].z, fmaf(C3, aa[j].w, Bl))));
                const float g = gelu_fast(x);
                const float gm = (idx < wcnt) ? g : 0.0f;   // pad-slot guard
                if (j & 1) accB += gm; else accA += gm;
            }
        }
    } else {
        // fallback (~never): same merged loop straight from global
        const float4* p = A + o0;        // +16 pad makes overread safe
        for (int i = 0; i < wcnt; i += 8) {
            float4 aa[8];
#pragma unroll
            for (int j = 0; j < 8; ++j) aa[j] = p[i + j];
#pragma unroll
            for (int j = 0; j < 8; ++j) {
                const int idx = i + j;
                while (q < 4 && idx == nextEnd) FLUSH_ROW();
                const float x = fmaf(C0, aa[j].x, fmaf(C1, aa[j].y,
                                  fmaf(C2, aa[j].z, fmaf(C3, aa[j].w, Bl))));
                const float g = gelu_fast(x);
                const float gm = (idx < wcnt) ? g : 0.0f;
                if (j & 1) accB += gm; else accA += gm;
            }
        }
    }
    while (q < 4) FLUSH_ROW();
#undef FLUSH_ROW

    // keep wcol loads out of phase 1 (register-pressure fence)
    __builtin_amdgcn_sched_barrier(0);

    // Phase 2: lane c owns W2[:,c]; each wave finishes its own 4 nodes.
    float wcol[64];
#pragma unroll
    for (int k = 0; k < 64; ++k) wcol[k] = W2[k * HALF + lane];

#pragma unroll
    for (int qq = 0; qq < 4; ++qq) {
        const int n = n0 + qq;
        if (n < N) {
            const float* shrow = sh + (w * 4 + qq) * 64;
            float oA = 0.0f, oB = 0.0f, oC = 0.0f, oD = 0.0f;
#pragma unroll
            for (int k4 = 0; k4 < 16; ++k4) {
                const float4 hv = *(const float4*)(shrow + k4 * 4);
                oA = fmaf(hv.x, wcol[4 * k4 + 0], oA);
                oB = fmaf(hv.y, wcol[4 * k4 + 1], oB);
                oC = fmaf(hv.z, wcol[4 * k4 + 2], oC);
                oD = fmaf(hv.w, wcol[4 * k4 + 3], oD);
            }
            const int cq = (qq == 0) ? c0 : (qq == 1) ? c1 : (qq == 2) ? c2 : c3;
            const float res = (cq > 0) ? ((oA + oB) + (oC + oD)) + b2l : 0.0f;
            float* orow = out + (size_t)n * (2 * HALF);
            orow[lane] = res;
            orow[HALF + lane] = 0.0f;
        }
    }
}

// ---------------------------------------------------------------------------
extern "C" void kernel_launch(void* const* d_in, const int* in_sizes, int n_in,
                              void* d_out, int out_size, void* d_ws, size_t ws_size,
                              hipStream_t stream) {
    const float* pos = (const float*)d_in[0];
    const int*   ei  = (const int*)d_in[1];
    // d_in[2] = batch (unused)
    const float* W1  = (const float*)d_in[3];
    const float* b1  = (const float*)d_in[4];
    const float* g   = (const float*)d_in[5];
    const float* b   = (const float*)d_in[6];
    const float* W2  = (const float*)d_in[7];
    const float* b2  = (const float*)d_in[8];
    float* out = (float*)d_out;

    const int N = in_sizes[0] / 3;
    const int E = in_sizes[1] / 2;

    // workspace: A[E+16] f4 | cursor[N] | stat[32] | offsets[N+1] | fp[16]
    float4* A      = (float4*)d_ws;
    int* cursor    = (int*)(A + E + 16);
    int* stat      = cursor + N;
    int* offsets   = stat + 32;
    float* fparams = (float*)(offsets + N + 1);

    const int nb = (N + 4095) / 4096;    // 25 for N=100k (all co-resident)

    hipMemsetAsync(cursor, 0, (size_t)(N + 32) * sizeof(int), stream);
    hist_kernel<<<(E / 4 + 255) / 256, 256, 0, stream>>>(ei + E, cursor, E);
    scan_kernel<<<nb, 1024, 0, stream>>>(cursor, cursor, offsets, stat,
                                         W1, b1, fparams, N);
    fill_kernel<<<(E / 4 + 255) / 256, 256, 0, stream>>>(ei, pos, fparams,
                                                         cursor, A, E);
    nodeout_kernel<<<(N + 15) / 16, 256, 0, stream>>>(A, offsets, W1, b1, g, b,
                                                      W2, b2, fparams, out, N);
}

// Round 4
// 257.951 us; speedup vs baseline: 1.1793x; 1.1793x over previous
//
#include <hip/hip_runtime.h>
#include <math.h>

#define HALF 64
#define LN_EPS 1e-5f
#define SA_CAP 640   // staged edges per block (10 KB f4); Poisson(256)+24sigma

// gelu_tanh(x) = x * sigmoid(1.5957691*x + 0.0713549*x^3)
#define GC0 -2.3022082f
#define GC1 -0.1029438f

__device__ __forceinline__ float gelu_fast(float x) {
    const float x2 = x * x;
    const float z  = x * fmaf(GC1, x2, GC0);
    const float e  = __builtin_amdgcn_exp2f(z);
    const float sg = __builtin_amdgcn_rcpf(1.0f + e);
    return x * sg;
}

// ---------------------------------------------------------------------------
// histogram of dst; atomic return value IS the edge's rank in its bucket
// (rank restored: r3's fused-atomic fill put a ~400cy L2 RMW into every
// store's dependency chain at VGPR=16 -> 92us, VALUBusy 3.6%. Atomic-free
// fill was the measured-good pattern.)
// ---------------------------------------------------------------------------
__global__ void __launch_bounds__(256) hist_kernel(
    const int* __restrict__ dst, int* __restrict__ cursor,
    int* __restrict__ rank, int E)
{
    const int e4 = (blockIdx.x * 256 + threadIdx.x) * 4;
    if (e4 + 3 < E) {
        const int4 d = *(const int4*)(dst + e4);
        int4 r;
        r.x = atomicAdd(&cursor[d.x], 1);
        r.y = atomicAdd(&cursor[d.y], 1);
        r.z = atomicAdd(&cursor[d.z], 1);
        r.w = atomicAdd(&cursor[d.w], 1);
        *(int4*)(rank + e4) = r;
    } else {
        for (int e = e4; e < E; ++e) rank[e] = atomicAdd(&cursor[dst[e]], 1);
    }
}

// ---------------------------------------------------------------------------
// PARALLEL exclusive scan (decoupled lookback) -> offsets[]. Block 0 wave 0
// also computes the analytic-LN constants fp[0..13].
// ---------------------------------------------------------------------------
__global__ void __launch_bounds__(1024) scan_kernel(
    const int* __restrict__ cursor, int* __restrict__ offsets,
    int* __restrict__ stat,
    const float* __restrict__ W1, const float* __restrict__ b1,
    float* __restrict__ fp, int N)
{
    const int t = threadIdx.x;
    const int b = blockIdx.x;
    if (b == 0 && t < 64) {
        const float w0 = W1[t], w1 = W1[HALF + t], w2 = W1[2 * HALF + t], bb = b1[t];
        float v[14] = { w0, w1, w2, bb,
                        w0 * w0, w0 * w1, w0 * w2, w1 * w1, w1 * w2, w2 * w2,
                        w0 * bb, w1 * bb, w2 * bb, bb * bb };
#pragma unroll
        for (int j = 0; j < 14; ++j) {
            float s = v[j];
#pragma unroll
            for (int off = 32; off; off >>= 1) s += __shfl_down(s, off, 64);
            if (t == 0) fp[j] = s * (1.0f / 64.0f);
        }
    }

    __shared__ int wtot[16];
    __shared__ int wexc[16];
    __shared__ int stot;
    __shared__ int sPref;
    const int w = t >> 6, lane = t & 63;

    const int i0 = b * 4096 + t * 4;
    int c[4];
    if (i0 + 3 < N) {
        *(int4*)c = *(const int4*)(cursor + i0);
    } else {
#pragma unroll
        for (int j = 0; j < 4; ++j) c[j] = (i0 + j < N) ? cursor[i0 + j] : 0;
    }
    const int s = c[0] + c[1] + c[2] + c[3];
    int incl = s;
#pragma unroll
    for (int off = 1; off < 64; off <<= 1) {
        const int v = __shfl_up(incl, off, 64);
        if (lane >= off) incl += v;
    }
    if (lane == 63) wtot[w] = incl;
    __syncthreads();
    if (t < 16) {
        const int v = wtot[t];
        int inc2 = v;
#pragma unroll
        for (int off = 1; off < 16; off <<= 1) {
            const int u = __shfl_up(inc2, off, 64);
            if (t >= off) inc2 += u;
        }
        wexc[t] = inc2 - v;
        if (t == 15) stot = inc2;
    }
    __syncthreads();

    if (t == 0) {
        const int S = stot;
        if (b == 0) {
            sPref = 0;
            __hip_atomic_store(&stat[0], (S << 2) | 2, __ATOMIC_RELEASE,
                               __HIP_MEMORY_SCOPE_AGENT);
        } else {
            __hip_atomic_store(&stat[b], (S << 2) | 1, __ATOMIC_RELEASE,
                               __HIP_MEMORY_SCOPE_AGENT);
            int running = 0;
            int j = b - 1;
            while (true) {
                const int v = __hip_atomic_load(&stat[j], __ATOMIC_ACQUIRE,
                                                __HIP_MEMORY_SCOPE_AGENT);
                const int st = v & 3;
                if (st == 0) continue;          // predecessor not published yet
                running += v >> 2;
                if (st == 2) break;             // hit a full prefix
                --j;
            }
            sPref = running;
            __hip_atomic_store(&stat[b], ((running + S) << 2) | 2,
                               __ATOMIC_RELEASE, __HIP_MEMORY_SCOPE_AGENT);
        }
    }
    __syncthreads();

    int run = sPref + wexc[w] + (incl - s);
#pragma unroll
    for (int j = 0; j < 4; ++j) {
        const int i = i0 + j;
        if (i < N) offsets[i] = run;
        run += c[j];
    }
    if (t == 0 && b == (int)gridDim.x - 1) offsets[N] = sPref + stot;
}

// ---------------------------------------------------------------------------
// fill_idx (atomic-free): srcidx[offsets[dst]+rank] = src. 4-byte scatter
// (vs r3's 16B geometry scatter = 102.5 MB HBM writes at 64B-line granu-
// larity). Geometry moved into nodeout's stage pre-pass; A array deleted.
// ---------------------------------------------------------------------------
__global__ void __launch_bounds__(256) fillidx_kernel(
    const int* __restrict__ ei, const int* __restrict__ rank,
    const int* __restrict__ offsets, int* __restrict__ srcidx, int E)
{
    const int e4 = (blockIdx.x * 256 + threadIdx.x) * 4;
    if (e4 >= E) return;
    if (e4 + 3 < E) {
        const int4 s = *(const int4*)(ei + e4);
        const int4 d = *(const int4*)(ei + E + e4);
        const int4 r = *(const int4*)(rank + e4);
        srcidx[offsets[d.x] + r.x] = s.x;
        srcidx[offsets[d.y] + r.y] = s.y;
        srcidx[offsets[d.z] + r.z] = s.z;
        srcidx[offsets[d.w] + r.w] = s.w;
    } else {
        for (int e = e4; e < E; ++e)
            srcidx[offsets[ei[E + e]] + rank[e]] = ei[e];
    }
}

// ---------------------------------------------------------------------------
// FUSED geometry+node+out kernel v5: 16 nodes/block, 4 waves x 4 nodes.
// Pre-pass: 256 threads cooperatively build the block's geometry tile in LDS
// directly from pos (~1 edge/thread): srcidx coalesced, pos[src] gathered
// (pos = 1.2 MB, XCD-L2 resident), pos[dst] block-local in LDS. This deletes
// the 25.6 MB A array (102 MB amplified HBM writes + reads).
// Phase 1: merged 4-node chunk-of-8 stream per wave (v4).
// Phase 2: wave-private, lane c holds W2[:,c] in VGPRs (v4).
// ---------------------------------------------------------------------------
__global__ void __launch_bounds__(256, 4) nodeout_kernel(
    const int* __restrict__ srcidx,      // [E+16] CSR-ordered src ids
    const int* __restrict__ offsets,     // [N+1]
    const float* __restrict__ pos,
    const float* __restrict__ W1, const float* __restrict__ b1,
    const float* __restrict__ ln_g, const float* __restrict__ ln_b,
    const float* __restrict__ W2, const float* __restrict__ b2,
    const float* __restrict__ fp,
    float* __restrict__ out, int N)
{
    __shared__ float4 sA[SA_CAP + 8];    // 10.4 KB geometry tile (+pad)
    __shared__ float  sh[16 * 64];       // 4 KB mean rows
    __shared__ int    sOff[17];
    __shared__ float4 sPd[16];           // dst positions

    const int tid = threadIdx.x;
    const int lane = tid & 63, w = tid >> 6;
    const int base = blockIdx.x * 16;

    if (tid < 17) sOff[tid] = offsets[(base + tid < N) ? base + tid : N];
    if (tid < 16) {
        const int n = base + tid;
        if (n < N)
            sPd[tid] = make_float4(pos[3 * n], pos[3 * n + 1], pos[3 * n + 2], 0.0f);
    }

    // phase-1 per-lane constants
    const float gl = ln_g[lane];
    const float C0 = gl * (W1[lane]            - fp[0]);
    const float C1 = gl * (W1[HALF + lane]     - fp[1]);
    const float C2 = gl * (W1[2 * HALF + lane] - fp[2]);
    const float C3 = gl * (b1[lane]            - fp[3]);
    const float Bl = ln_b[lane];
    const float b2l = b2[lane];

    // geometry constants (uniform -> SGPRs)
    const float ux = fp[0], uy = fp[1], uz = fp[2], cc = fp[3];
    const float Gxx = fp[4], Gxy = fp[5], Gxz = fp[6];
    const float Gyy = fp[7], Gyz = fp[8], Gzz = fp[9];
    const float px = fp[10], py = fp[11], pz = fp[12], q13 = fp[13];

    const int nend = (base + 16 < N) ? base + 16 : N;
    const int begB = offsets[base];
    const int cntB = offsets[nend] - begB;

    // wave's 4-node CSR bounds
    const int n0 = base + w * 4;
    const int o0 = offsets[(n0     < N) ? n0     : N];
    const int o1 = offsets[(n0 + 1 < N) ? n0 + 1 : N];
    const int o2 = offsets[(n0 + 2 < N) ? n0 + 2 : N];
    const int o3 = offsets[(n0 + 3 < N) ? n0 + 3 : N];
    const int o4 = offsets[(n0 + 4 < N) ? n0 + 4 : N];
    const int c0 = o1 - o0, c1 = o2 - o1, c2 = o3 - o2, c3 = o4 - o3;
    const int e1 = c0, e2 = c0 + c1, e3 = c0 + c1 + c2;
    const int wcnt = c0 + c1 + c2 + c3;
    const float i0 = (c0 > 0) ? 1.0f / (float)c0 : 0.0f;
    const float i1 = (c1 > 0) ? 1.0f / (float)c1 : 0.0f;
    const float i2 = (c2 > 0) ? 1.0f / (float)c2 : 0.0f;
    const float i3 = (c3 > 0) ? 1.0f / (float)c3 : 0.0f;
    const int off = o0 - begB;

    __syncthreads();                      // sOff / sPd visible

    // geometry pre-pass for tile [t0, t0+tcnt): 1 edge/thread avg
#define PREPASS(T0, TCNT)                                                   \
    for (int i = tid; i < (TCNT); i += 256) {                               \
        const int slot = begB + (T0) + i;                                   \
        const int s = srcidx[slot];                                         \
        int qd = 0;                                                         \
        _Pragma("unroll")                                                   \
        for (int k = 1; k < 16; ++k) qd += (slot >= sOff[k]) ? 1 : 0;       \
        const float4 pd = sPd[qd];                                          \
        const float rx0 = pd.x - pos[3 * s];                                \
        const float ry0 = pd.y - pos[3 * s + 1];                            \
        const float rz0 = pd.z - pos[3 * s + 2];                            \
        const float dist = sqrtf(rx0 * rx0 + ry0 * ry0 + rz0 * rz0);        \
        const float invd = 1.0f / (dist + 1e-6f);                           \
        const float rx = rx0 * invd, ry = ry0 * invd, rz = rz0 * invd;      \
        const float mu  = fmaf(ux, rx, fmaf(uy, ry, fmaf(uz, rz, cc)));     \
        const float ev2 = Gxx * rx * rx + Gyy * ry * ry + Gzz * rz * rz     \
                        + 2.0f * (Gxy * rx * ry + Gxz * rx * rz             \
                                  + Gyz * ry * rz + px * rx + py * ry       \
                                  + pz * rz) + q13;                         \
        const float rstd = rsqrtf(ev2 - mu * mu + LN_EPS);                  \
        sA[i] = make_float4(rx * rstd, ry * rstd, rz * rstd, rstd);         \
    }

    if (cntB <= SA_CAP) {
        // ---- fast path ----
        PREPASS(0, cntB)
        __syncthreads();

        int q = 0, nextEnd = e1;
        float accA = 0.0f, accB = 0.0f;
#define FLUSH_ROW()                                                         \
        {                                                                   \
            const float inv = (q == 0) ? i0 : (q == 1) ? i1 : (q == 2) ? i2 : i3; \
            sh[(w * 4 + q) * 64 + lane] = (accA + accB) * inv;              \
            accA = 0.0f; accB = 0.0f; ++q;                                  \
            nextEnd = (q == 1) ? e2 : (q == 2) ? e3 : (q == 3) ? wcnt : 0x7fffffff; \
        }
        for (int i = 0; i < wcnt; i += 8) {
            float4 aa[8];
#pragma unroll
            for (int j = 0; j < 8; ++j) aa[j] = sA[off + i + j];
#pragma unroll
            for (int j = 0; j < 8; ++j) {
                const int idx = i + j;
                while (q < 4 && idx == nextEnd) FLUSH_ROW();
                const float x = fmaf(C0, aa[j].x, fmaf(C1, aa[j].y,
                                  fmaf(C2, aa[j].z, fmaf(C3, aa[j].w, Bl))));
                const float g = gelu_fast(x);
                const float gm = (idx < wcnt) ? g : 0.0f;   // pad-slot guard
                if (j & 1) accB += gm; else accA += gm;
            }
        }
        while (q < 4) FLUSH_ROW();
#undef FLUSH_ROW
    } else {
        // ---- fallback: tiled (block-uniform, astronomically rare) ----
        float fa0 = 0.0f, fa1 = 0.0f, fa2 = 0.0f, fa3 = 0.0f;
        for (int t0 = 0; t0 < cntB; t0 += SA_CAP) {
            const int tcnt = (cntB - t0 < SA_CAP) ? cntB - t0 : SA_CAP;
            PREPASS(t0, tcnt)
            __syncthreads();
#define ACCUM(FA, LO, HI)                                                   \
            {                                                               \
                int lo = off + (LO); if (lo < t0) lo = t0;                  \
                int hi = off + (HI); if (hi > t0 + tcnt) hi = t0 + tcnt;    \
                for (int i = lo; i < hi; ++i) {                             \
                    const float4 a = sA[i - t0];                            \
                    const float x = fmaf(C0, a.x, fmaf(C1, a.y,             \
                                      fmaf(C2, a.z, fmaf(C3, a.w, Bl))));   \
                    FA += gelu_fast(x);                                     \
                }                                                           \
            }
            ACCUM(fa0, 0,  e1)
            ACCUM(fa1, e1, e2)
            ACCUM(fa2, e2, e3)
            ACCUM(fa3, e3, wcnt)
#undef ACCUM
            __syncthreads();             // protect sA for next tile
        }
        sh[(w * 4 + 0) * 64 + lane] = fa0 * i0;
        sh[(w * 4 + 1) * 64 + lane] = fa1 * i1;
        sh[(w * 4 + 2) * 64 + lane] = fa2 * i2;
        sh[(w * 4 + 3) * 64 + lane] = fa3 * i3;
    }
#undef PREPASS

    // keep wcol loads out of phase 1 (register-pressure fence)
    __builtin_amdgcn_sched_barrier(0);

    // Phase 2: lane c owns W2[:,c]; each wave finishes its own 4 nodes.
    float wcol[64];
#pragma unroll
    for (int k = 0; k < 64; ++k) wcol[k] = W2[k * HALF + lane];

#pragma unroll
    for (int qn = 0; qn < 4; ++qn) {
        const int n = n0 + qn;
        if (n < N) {
            const float* shrow = sh + (w * 4 + qn) * 64;
            float oA = 0.0f, oB = 0.0f, oC = 0.0f, oD = 0.0f;
#pragma unroll
            for (int k4 = 0; k4 < 16; ++k4) {
                const float4 hv = *(const float4*)(shrow + k4 * 4);
                oA = fmaf(hv.x, wcol[4 * k4 + 0], oA);
                oB = fmaf(hv.y, wcol[4 * k4 + 1], oB);
                oC = fmaf(hv.z, wcol[4 * k4 + 2], oC);
                oD = fmaf(hv.w, wcol[4 * k4 + 3], oD);
            }
            const int cq = (qn == 0) ? c0 : (qn == 1) ? c1 : (qn == 2) ? c2 : c3;
            const float res = (cq > 0) ? ((oA + oB) + (oC + oD)) + b2l : 0.0f;
            float* orow = out + (size_t)n * (2 * HALF);
            orow[lane] = res;
            orow[HALF + lane] = 0.0f;
        }
    }
}

// ---------------------------------------------------------------------------
extern "C" void kernel_launch(void* const* d_in, const int* in_sizes, int n_in,
                              void* d_out, int out_size, void* d_ws, size_t ws_size,
                              hipStream_t stream) {
    const float* pos = (const float*)d_in[0];
    const int*   ei  = (const int*)d_in[1];
    // d_in[2] = batch (unused)
    const float* W1  = (const float*)d_in[3];
    const float* b1  = (const float*)d_in[4];
    const float* g   = (const float*)d_in[5];
    const float* b   = (const float*)d_in[6];
    const float* W2  = (const float*)d_in[7];
    const float* b2  = (const float*)d_in[8];
    float* out = (float*)d_out;

    const int N = in_sizes[0] / 3;
    const int E = in_sizes[1] / 2;

    // workspace: srcidx[E+16] | cursor[N] | stat[32] | offsets[N+1] | fp[16] | rank[E]
    int* srcidx    = (int*)d_ws;
    int* cursor    = srcidx + E + 16;
    int* stat      = cursor + N;
    int* offsets   = stat + 32;
    float* fparams = (float*)(offsets + N + 1);
    int* rank      = (int*)(fparams + 16);

    const int nb = (N + 4095) / 4096;    // 25 for N=100k (all co-resident)

    hipMemsetAsync(cursor, 0, (size_t)(N + 32) * sizeof(int), stream);
    hist_kernel<<<(E / 4 + 255) / 256, 256, 0, stream>>>(ei + E, cursor, rank, E);
    scan_kernel<<<nb, 1024, 0, stream>>>(cursor, offsets, stat, W1, b1,
                                         fparams, N);
    fillidx_kernel<<<(E / 4 + 255) / 256, 256, 0, stream>>>(ei, rank, offsets,
                                                            srcidx, E);
    nodeout_kernel<<<(N + 15) / 16, 256, 0, stream>>>(srcidx, offsets, pos,
                                                      W1, b1, g, b, W2, b2,
                                                      fparams, out, N);
}